// Round 1
// baseline (711.406 us; speedup 1.0000x reference)
//
#include <hip/hip_runtime.h>

// SpectralConv2d as 4 dense partial-DFT GEMMs (bf16 MFMA) + fp32 channel mix.
// B=16, Cin=Cout=64, H=W=256, modes 32x32.
//
// ws layout (bytes):
//   [0      ) F2t  ushort[64][256]   : B-op of stage A   (32 KB)
//   [32768  ) F1e  ushort[64][512]   : A-op of stage B   (64 KB)
//   [98304  ) G1   ushort[512][64]   : A-op of stage C   (64 KB)
//   [163840 ) G2t  ushort[256][64]   : B-op of stage D   (32 KB)
//   [196608 ) Y    float[16][64][64][32]  (8 MB)
//   [8585216) Mx   ushort[16][64][64][32] (4 MB)
//   total 12779520 B

#define H_ 256
#define W_ 256

typedef short short8 __attribute__((ext_vector_type(8)));
typedef float floatx4 __attribute__((ext_vector_type(4)));

static __device__ __forceinline__ unsigned short f2b(float f) {
    union { float f; unsigned int u; } v; v.f = f;
    unsigned int r = v.u + 0x7FFFu + ((v.u >> 16) & 1u);
    return (unsigned short)(r >> 16);
}

// ---------------- K0: twiddle tables (fp64 -> bf16) ----------------
__global__ void build_tables(unsigned short* ws) {
    int k = blockIdx.x;      // mode index 0..31
    int n = threadIdx.x;     // position 0..255
    int u = (k * n) & 255;
    double ang = 6.283185307179586476925286766559 * (double)u / 256.0;
    float c = (float)cos(ang), s = (float)sin(ang);
    unsigned short bc = f2b(c), bs = f2b(s), bns = f2b(-s);
    unsigned short* F2t = ws;                    // [2ky+c][w]
    unsigned short* F1e = ws + 16384;            // [2kx+c][2h+c']
    unsigned short* G1  = ws + 16384 + 32768;    // [2h+c'][2kx+c]
    unsigned short* G2t = ws + 16384 + 65536;    // [w][2ky+c]

    // Stage A (forward DFT over w, e^{-i}): Tr=sum x*cos, Ti=-sum x*sin
    F2t[(2 * k) * 256 + n]     = bc;
    F2t[(2 * k + 1) * 256 + n] = bns;
    // Stage B (forward DFT over h, e^{-i}, complex T):
    // Yre = sum c*Tr + s*Ti ; Yim = sum c*Ti - s*Tr
    F1e[(2 * k) * 512 + 2 * n]         = bc;
    F1e[(2 * k) * 512 + 2 * n + 1]     = bs;
    F1e[(2 * k + 1) * 512 + 2 * n]     = bns;
    F1e[(2 * k + 1) * 512 + 2 * n + 1] = bc;
    // Stage C (inverse DFT over kx, e^{+i}): Zre = c*Mr - s*Mi ; Zim = s*Mr + c*Mi
    G1[(2 * n) * 64 + 2 * k]         = bc;
    G1[(2 * n) * 64 + 2 * k + 1]     = bns;
    G1[(2 * n + 1) * 64 + 2 * k]     = bs;
    G1[(2 * n + 1) * 64 + 2 * k + 1] = bc;
    // Stage D (irfft over ky): out = sum fac*(Zr*cos - Zi*sin), fac = ky?2:1
    float fac = (k == 0) ? 1.f : 2.f;
    G2t[n * 64 + 2 * k]     = f2b(fac * c);
    G2t[n * 64 + 2 * k + 1] = f2b(-fac * s);
}

// ---------------- K1: forward, fused stages A+B, one block per (b,i) ----------------
__global__ __launch_bounds__(256) void fwd_kernel(const float* __restrict__ x,
                                                  const unsigned short* __restrict__ ws_u,
                                                  float* __restrict__ Y) {
    __shared__ __align__(16) unsigned short lA[256 * 64];   // x chunk bf16 [h][w-chunk]
    __shared__ __align__(16) unsigned short lB[64 * 64];    // F2t chunk [ky2][w-chunk]
    __shared__ __align__(16) unsigned short lT[32 * 512];   // T2 [ky][h2]
    __shared__ __align__(16) unsigned short lF1[64 * 512];  // F1e table
    const int tid = threadIdx.x;
    const int wave = tid >> 6, lane = tid & 63;
    const int lm = lane & 15, lq = lane >> 4;
    const int bi = blockIdx.x;

    { // F1e table -> LDS (needed only after several syncs)
        const uint4* src = (const uint4*)(ws_u + 16384);
        uint4* dst = (uint4*)lF1;
        for (int idx = tid; idx < 4096; idx += 256) dst[idx] = src[idx];
    }

    floatx4 acc[4][4];
    for (int a = 0; a < 4; ++a)
        for (int b = 0; b < 4; ++b) acc[a][b] = (floatx4){0.f, 0.f, 0.f, 0.f};

    const float* xg = x + (size_t)bi * (H_ * W_);
    for (int kc = 0; kc < 4; ++kc) {
        __syncthreads();  // protect lA/lB from previous iteration's readers
        // stage x chunk (fp32 global -> bf16 LDS), rows 0..255, cols kc*64..+63
        for (int q = 0; q < 16; ++q) {
            int idx = q * 256 + tid;          // 0..4095
            int row = idx >> 4, c4 = idx & 15;
            const float4 v = *(const float4*)(xg + row * 256 + kc * 64 + c4 * 4);
            ushort4 b4;
            b4.x = f2b(v.x); b4.y = f2b(v.y); b4.z = f2b(v.z); b4.w = f2b(v.w);
            *(ushort4*)(lA + row * 64 + c4 * 4) = b4;
        }
        // stage F2t chunk [64 ky2-rows][64 w]
        for (int t2 = 0; t2 < 2; ++t2) {
            int idx = t2 * 256 + tid;         // 0..511
            int row = idx >> 3, qq = idx & 7;
            *(uint4*)(lB + row * 64 + qq * 8) =
                *(const uint4*)(ws_u + row * 256 + kc * 64 + qq * 8);
        }
        __syncthreads();
        for (int kk = 0; kk < 2; ++kk) {
            short8 af[4], bf[4];
            for (int a = 0; a < 4; ++a) {
                int mt = wave * 4 + a;
                af[a] = *(const short8*)(lA + (mt * 16 + lm) * 64 + kk * 32 + lq * 8);
            }
            for (int b = 0; b < 4; ++b)
                bf[b] = *(const short8*)(lB + (b * 16 + lm) * 64 + kk * 32 + lq * 8);
            for (int a = 0; a < 4; ++a)
                for (int b = 0; b < 4; ++b)
                    acc[a][b] = __builtin_amdgcn_mfma_f32_16x16x32_bf16(af[a], bf[b], acc[a][b], 0, 0, 0);
        }
    }
    __syncthreads();
    // write T2 into lT as [ky][h2=2h+c] bf16 (stage B's B-operand layout)
    for (int a = 0; a < 4; ++a) {
        int mbase = (wave * 4 + a) * 16 + lq * 4;
        for (int b = 0; b < 4; ++b) {
            int col = b * 16 + lm;            // 2ky+c
            int ky = col >> 1, c = col & 1;
            for (int r = 0; r < 4; ++r) {
                int h = mbase + r;
                lT[ky * 512 + 2 * h + c] = f2b(acc[a][b][r]);
            }
        }
    }
    __syncthreads();
    // stage B: Y[64][32] = F1e[64][512] x T2[512][32]; wave -> m-tile, nt 0..1
    floatx4 acc2[2];
    acc2[0] = (floatx4){0.f, 0.f, 0.f, 0.f};
    acc2[1] = (floatx4){0.f, 0.f, 0.f, 0.f};
    for (int ks = 0; ks < 16; ++ks) {
        short8 af = *(const short8*)(lF1 + (wave * 16 + lm) * 512 + ks * 32 + lq * 8);
        for (int b = 0; b < 2; ++b) {
            short8 bf = *(const short8*)(lT + (b * 16 + lm) * 512 + ks * 32 + lq * 8);
            acc2[b] = __builtin_amdgcn_mfma_f32_16x16x32_bf16(af, bf, acc2[b], 0, 0, 0);
        }
    }
    float* Yg = Y + (size_t)bi * (64 * 32);
    for (int b = 0; b < 2; ++b) {
        int colk = b * 16 + lm;               // ky
        int mrow = wave * 16 + lq * 4;        // kx2
        for (int r = 0; r < 4; ++r)
            Yg[(mrow + r) * 32 + colk] = acc2[b][r];
    }
}

// ---------------- K2: channel mix (fp32), one block per (b,kx) ----------------
__global__ __launch_bounds__(256) void mix_kernel(const float* __restrict__ Wg,
                                                  const float* __restrict__ Y,
                                                  unsigned short* __restrict__ Mx) {
    __shared__ float Yb[64][2][32];   // [i][c][ky]
    const int b = blockIdx.x, kx = blockIdx.y;
    const int tid = threadIdx.x;
    for (int q = 0; q < 16; ++q) {
        int idx = q * 256 + tid;      // 0..4095
        int i = idx >> 6, rem = idx & 63, c = rem >> 5, ky = rem & 31;
        Yb[i][c][ky] = Y[(((size_t)b * 64 + i) * 64 + (2 * kx + c)) * 32 + ky];
    }
    __syncthreads();
    const int ky = tid & 31, o2 = tid >> 5;   // o2 0..7
    const float scale = 1.f / 65536.f;        // 1/(H*W): ifft+irfft normalization
    for (int oo = 0; oo < 8; ++oo) {
        int o = o2 * 8 + oo;
        float ar = 0.f, ai = 0.f;
        for (int i = 0; i < 64; ++i) {
            float w = Wg[(size_t)(i * 64 + o) * 1024 + kx * 32 + ky];
            ar += Yb[i][0][ky] * w;
            ai += Yb[i][1][ky] * w;
        }
        unsigned short* dst = Mx + ((size_t)(b * 64 + o) * 64 + 2 * kx) * 32 + ky;
        dst[0]  = f2b(ar * scale);
        dst[32] = f2b(ai * scale);
    }
}

// ---------------- K3: inverse, fused stages C+D, one block per (b,o) ----------------
__global__ __launch_bounds__(256) void inv_kernel(const unsigned short* __restrict__ ws_u,
                                                  const unsigned short* __restrict__ Mx,
                                                  const float* __restrict__ bias,
                                                  float* __restrict__ out) {
    __shared__ __align__(16) unsigned short lG1[512 * 64];  // 64 KB
    __shared__ __align__(16) unsigned short lG2[256 * 64];  // 32 KB [w][ky2]
    __shared__ __align__(16) unsigned short lMx[64 * 32];   // 4 KB  [kx2][ky]
    __shared__ __align__(16) unsigned short lZ[256 * 64];   // 32 KB [h][ky2]
    const int tid = threadIdx.x;
    const int wave = tid >> 6, lane = tid & 63;
    const int lm = lane & 15, lq = lane >> 4;
    const int bo = blockIdx.x;
    const int o = bo & 63;

    {
        const uint4* srcG1 = (const uint4*)(ws_u + 49152);
        uint4* d1 = (uint4*)lG1;
        for (int idx = tid; idx < 4096; idx += 256) d1[idx] = srcG1[idx];
        const uint4* srcG2 = (const uint4*)(ws_u + 81920);
        uint4* d2 = (uint4*)lG2;
        for (int idx = tid; idx < 2048; idx += 256) d2[idx] = srcG2[idx];
        const uint4* srcM = (const uint4*)(Mx + (size_t)bo * 2048);
        uint4* d3 = (uint4*)lMx;
        for (int idx = tid; idx < 256; idx += 256) d3[idx] = srcM[idx];
    }
    __syncthreads();

    // stage C: Z2[512][32] = G1[512][64] x Mx2[64][32]; wave -> 8 m-tiles, 2 n-tiles
    {
        floatx4 accc[8][2];
        for (int a = 0; a < 8; ++a)
            for (int b = 0; b < 2; ++b) accc[a][b] = (floatx4){0.f, 0.f, 0.f, 0.f};
        for (int ks = 0; ks < 2; ++ks) {
            short8 bf[2];
            for (int b = 0; b < 2; ++b) {
                int n = b * 16 + lm;          // ky
                short8 t;
                for (int j = 0; j < 8; ++j)
                    t[j] = (short)lMx[(ks * 32 + lq * 8 + j) * 32 + n];
                bf[b] = t;
            }
            for (int a = 0; a < 8; ++a) {
                int mt = wave * 8 + a;
                short8 af = *(const short8*)(lG1 + (mt * 16 + lm) * 64 + ks * 32 + lq * 8);
                for (int b = 0; b < 2; ++b)
                    accc[a][b] = __builtin_amdgcn_mfma_f32_16x16x32_bf16(af, bf[b], accc[a][b], 0, 0, 0);
            }
        }
        // Z -> lZ [h][2ky+c]  (stage D's A-operand layout)
        for (int a = 0; a < 8; ++a) {
            int mbase = (wave * 8 + a) * 16 + lq * 4;
            for (int b = 0; b < 2; ++b) {
                int ky = b * 16 + lm;
                for (int r = 0; r < 4; ++r) {
                    int m = mbase + r;        // h2 = 2h + c
                    int h = m >> 1, c = m & 1;
                    lZ[h * 64 + 2 * ky + c] = f2b(accc[a][b][r]);
                }
            }
        }
    }
    __syncthreads();

    const float bv = bias[o];
    float* og = out + (size_t)bo * (H_ * W_);
    // stage D: out[256][256] = Z2[256][64] x G2t'[64][256], in 4 h-strips of 64
    for (int s = 0; s < 4; ++s) {
        floatx4 accd[4][4];
        for (int a = 0; a < 4; ++a)
            for (int b = 0; b < 4; ++b) accd[a][b] = (floatx4){0.f, 0.f, 0.f, 0.f};
        for (int ks = 0; ks < 2; ++ks) {
            short8 af[4], bf[4];
            for (int a = 0; a < 4; ++a) {
                int mt = s * 4 + a;
                af[a] = *(const short8*)(lZ + (mt * 16 + lm) * 64 + ks * 32 + lq * 8);
            }
            for (int b = 0; b < 4; ++b) {
                int nt = wave * 4 + b;
                bf[b] = *(const short8*)(lG2 + (nt * 16 + lm) * 64 + ks * 32 + lq * 8);
            }
            for (int a = 0; a < 4; ++a)
                for (int b = 0; b < 4; ++b)
                    accd[a][b] = __builtin_amdgcn_mfma_f32_16x16x32_bf16(af[a], bf[b], accd[a][b], 0, 0, 0);
        }
        for (int a = 0; a < 4; ++a) {
            int hbase = (s * 4 + a) * 16 + lq * 4;
            for (int b = 0; b < 4; ++b) {
                int w = (wave * 4 + b) * 16 + lm;
                for (int r = 0; r < 4; ++r)
                    og[(hbase + r) * 256 + w] = accd[a][b][r] + bv;
            }
        }
    }
}

extern "C" void kernel_launch(void* const* d_in, const int* in_sizes, int n_in,
                              void* d_out, int out_size, void* d_ws, size_t ws_size,
                              hipStream_t stream) {
    const float* x    = (const float*)d_in[0];
    const float* w    = (const float*)d_in[1];
    const float* bias = (const float*)d_in[2];
    float* out = (float*)d_out;
    unsigned short* ws_u = (unsigned short*)d_ws;
    float* Y = (float*)((char*)d_ws + 196608);
    unsigned short* Mx = (unsigned short*)((char*)d_ws + 8585216);

    build_tables<<<32, 256, 0, stream>>>(ws_u);
    fwd_kernel<<<1024, 256, 0, stream>>>(x, ws_u, Y);
    mix_kernel<<<dim3(16, 32), 256, 0, stream>>>(w, Y, Mx);
    inv_kernel<<<1024, 256, 0, stream>>>(ws_u, Mx, bias, out);
}